// Round 7
// baseline (365.896 us; speedup 1.0000x reference)
//
#include <hip/hip_runtime.h>
#include <stdint.h>

// Problem constants (fixed by the reference): B=8, H=W=64, C=256
#define CC 256
#define NN 4096           // H*W
#define MM 2048           // NN/2 (pooled)
#define BB 8
#define NROWS (BB*NN)     // 32768 query rows
#define PROWS (BB*MM)     // 16384 pooled rows

typedef __attribute__((ext_vector_type(8))) short    short8;   // 8 bf16
typedef __attribute__((ext_vector_type(8))) _Float16 half8;    // 8 fp16
typedef __attribute__((ext_vector_type(4))) float    float4v;

__device__ __forceinline__ unsigned short f2bf(float f) {
    unsigned int u = __float_as_uint(f);
    u += 0x7fffu + ((u >> 16) & 1u);
    return (unsigned short)(u >> 16);
}
__device__ __forceinline__ float bf2f(unsigned short h) {
    return __uint_as_float(((unsigned int)h) << 16);
}
__device__ __forceinline__ unsigned short f2h(float f) {
    union { _Float16 h; unsigned short u; } cv; cv.h = (_Float16)f; return cv.u;
}
__device__ __forceinline__ float h2f(unsigned short u) {
    union { _Float16 h; unsigned short u; } cv; cv.u = u; return (float)cv.h;
}

// ---------------------------------------------------------------------------
// xsplit: x (fp32) -> x_hi/x_lo (bf16 split), elementwise, once.
// ---------------------------------------------------------------------------
__global__ __launch_bounds__(256) void xsplit_kernel(
    const float* __restrict__ x,
    unsigned short* __restrict__ x_hi,
    unsigned short* __restrict__ x_lo)
{
    const size_t i = ((size_t)blockIdx.x*256 + threadIdx.x) * 8;
    float4v a0 = *(const float4v*)(x + i);
    float4v a1 = *(const float4v*)(x + i + 4);
    short8 h, l;
    #pragma unroll
    for (int j = 0; j < 4; ++j) {
        unsigned short h0 = f2bf(a0[j]);
        h[j]   = (short)h0; l[j]   = (short)f2bf(a0[j] - bf2f(h0));
        unsigned short h1 = f2bf(a1[j]);
        h[4+j] = (short)h1; l[4+j] = (short)f2bf(a1[j] - bf2f(h1));
    }
    *(short8*)(x_hi + i) = h;
    *(short8*)(x_lo + i) = l;
}

// ---------------------------------------------------------------------------
// wsplit: transpose + bf16 hi/lo split the three 256x256 weights once.
// wT_hi/wT_lo layout: [widx][outcol][k]  (MFMA B-frags 16B contiguous)
// ---------------------------------------------------------------------------
__global__ void wsplit_kernel(const float* __restrict__ w_theta,
                              const float* __restrict__ w_phi,
                              const float* __restrict__ w_g,
                              unsigned short* __restrict__ wT_hi,
                              unsigned short* __restrict__ wT_lo)
{
    __shared__ float tile[64][65];
    const int widx = blockIdx.z;
    const int kt = blockIdx.x, ct = blockIdx.y;
    const float* w = (widx == 0) ? w_theta : (widx == 1) ? w_phi : w_g;
    const int t  = threadIdx.x;
    const int tc = t & 63, tr = t >> 6;
    #pragma unroll
    for (int i = 0; i < 16; ++i) {
        const int lk = tr*16 + i;
        tile[lk][tc] = w[(size_t)(kt*64 + lk)*CC + ct*64 + tc];
    }
    __syncthreads();
    #pragma unroll
    for (int i = 0; i < 16; ++i) {
        const int lc = tr*16 + i;
        float v = tile[tc][lc];
        const int c = ct*64 + lc, k = kt*64 + tc;
        unsigned short hh = f2bf(v);
        size_t o = ((size_t)widx*CC + c)*CC + k;
        wT_hi[o] = hh;
        wT_lo[o] = f2bf(v - bf2f(hh));
    }
}

// ---------------------------------------------------------------------------
// proj_kernel v7: W slice staged ONCE (full K=256), then the block sweeps
// 4 row-blocks with NO further barriers (1 barrier/block total; W staging
// amortized 4x; A-loads pipeline freely across the sweep).
// Grid 1536 = 12 cv x 128 rg; XCD = rg%8 -> x rows L2-local across the
// 12 col-variants that reuse them.
// theta/phi: 3-pass split-bf16; g: 1-pass.
// ---------------------------------------------------------------------------
__global__ __launch_bounds__(256, 2) void proj_kernel(
    const unsigned short* __restrict__ x_hi,
    const unsigned short* __restrict__ x_lo,
    const unsigned short* __restrict__ wT_hi,
    const unsigned short* __restrict__ wT_lo,
    unsigned short* __restrict__ th,
    unsigned short* __restrict__ ph,
    unsigned short* __restrict__ g_t)
{
    __shared__ unsigned short wt_hi[64*264];   // [64 cols][256 k + 8 pad]
    __shared__ unsigned short wt_lo[64*264];

    const int tid  = threadIdx.x;
    const int rg   = blockIdx.x & 127;         // row-group (XCD = rg%8)
    const int cv   = blockIdx.x >> 7;          // 0..11 col-variant
    const int widx = cv >> 2;
    const int wc0  = (cv & 3) * 64;
    const bool split3 = (widx < 2);            // theta/phi 3-pass; g 1-pass

    {   // stage pre-split W^T slice [64 cols][256 k] ONCE (pure copy)
        const int j    = tid & 63;
        const int kseg = tid >> 6;             // 4 chunks of 64 shorts
        const size_t gbase = ((size_t)widx*CC + wc0 + j)*CC + kseg*64;
        const unsigned short* sh = wT_hi + gbase;
        unsigned short* dh = &wt_hi[j*264 + kseg*64];
        #pragma unroll
        for (int u = 0; u < 8; ++u)
            *(uint4*)(dh + u*8) = *(const uint4*)(sh + u*8);
        if (split3) {
            const unsigned short* sl = wT_lo + gbase;
            unsigned short* dl = &wt_lo[j*264 + kseg*64];
            #pragma unroll
            for (int u = 0; u < 8; ++u)
                *(uint4*)(dl + u*8) = *(const uint4*)(sl + u*8);
        }
    }
    __syncthreads();                           // the ONLY barrier

    const int wv   = tid >> 6;
    const int lane = tid & 63;
    const int quad = lane >> 4;
    const int l15  = lane & 15;

    for (int irb = 0; irb < 4; ++irb) {
        const int r0   = (rg*4 + irb) * 64;
        const int arow = r0 + wv*16 + l15;
        const unsigned short* axh = x_hi + (size_t)arow*CC + quad*8;
        const unsigned short* axl = x_lo + (size_t)arow*CC + quad*8;

        float4v acc[4];
        #pragma unroll
        for (int nf = 0; nf < 4; ++nf) acc[nf] = (float4v){0.f,0.f,0.f,0.f};

        #pragma unroll
        for (int ksf = 0; ksf < 8; ++ksf) {
            short8 a_hi = *(const short8*)(axh + ksf*32);
            short8 a_lo;
            if (split3) a_lo = *(const short8*)(axl + ksf*32);
            #pragma unroll
            for (int nf = 0; nf < 4; ++nf) {
                const int wrow = nf*16 + l15;
                short8 b_hi = *(const short8*)&wt_hi[wrow*264 + ksf*32 + quad*8];
                acc[nf] = __builtin_amdgcn_mfma_f32_16x16x32_bf16(a_hi, b_hi, acc[nf], 0,0,0);
                if (split3) {
                    short8 b_lo = *(const short8*)&wt_lo[wrow*264 + ksf*32 + quad*8];
                    acc[nf] = __builtin_amdgcn_mfma_f32_16x16x32_bf16(a_hi, b_lo, acc[nf], 0,0,0);
                    acc[nf] = __builtin_amdgcn_mfma_f32_16x16x32_bf16(a_lo, b_hi, acc[nf], 0,0,0);
                }
            }
        }

        const int rowbase = r0 + wv*16 + quad*4;
        if (widx == 0) {                       // theta: unpooled, fp16 single
            #pragma unroll
            for (int nf = 0; nf < 4; ++nf) {
                const int c = wc0 + nf*16 + l15;
                #pragma unroll
                for (int r = 0; r < 4; ++r)
                    th[(size_t)(rowbase + r)*CC + c] = f2h(acc[nf][r]);
            }
        } else if (widx == 1) {                // phi: pool row pairs, fp16
            #pragma unroll
            for (int nf = 0; nf < 4; ++nf) {
                const int c = wc0 + nf*16 + l15;
                #pragma unroll
                for (int rp = 0; rp < 2; ++rp) {
                    float v = fmaxf(acc[nf][2*rp], acc[nf][2*rp+1]);
                    const int prow = rowbase/2 + rp;   // rowbase even -> exact
                    ph[(size_t)prow*CC + c] = f2h(v);
                }
            }
        } else {                               // g: pool, bf16, transposed
            #pragma unroll
            for (int nf = 0; nf < 4; ++nf) {
                const int c = wc0 + nf*16 + l15;
                #pragma unroll
                for (int rp = 0; rp < 2; ++rp) {
                    float v = fmaxf(acc[nf][2*rp], acc[nf][2*rp+1]);
                    const int prow = rowbase/2 + rp;
                    const int bb = prow >> 11;
                    const int m  = prow & 2047;
                    g_t[((size_t)bb*CC + c)*MM + m] = f2bf(v);
                }
            }
        }
    }
}

// ---------------------------------------------------------------------------
// phimean: per-batch column mean of phi; 512 blocks (32 rows each).
// ---------------------------------------------------------------------------
__global__ void phimean_kernel(const unsigned short* __restrict__ ph,
                               float* __restrict__ phbar)
{
    const int b = blockIdx.x >> 6, chunk = blockIdx.x & 63;
    const int c = threadIdx.x;
    const size_t base = ((size_t)b*MM + chunk*32)*CC + c;
    float s = 0.f;
    for (int r = 0; r < 32; ++r) s += h2f(ph[base + (size_t)r*CC]);
    atomicAdd(&phbar[b*CC + c], s * (1.0f/MM));
}

// ---------------------------------------------------------------------------
// attn_kernel v7: single-barrier software pipeline.
//  iter kt: [barrier] -> S(kt) from phi dbuf  ||  PV(kt-1) from P dbuf
//           -> exp(kt)->P[kt&1] (overlaps PV MFMAs) -> stage phi(kt+1).
//  Barriers/tile: 1 (was 2). Batch = blockIdx&7 -> per-XCD L2 holds its
//  batch's phi+g. Shift softmax (theta.phibar+128, clamp +/-85), ones-MFMA l.
// ---------------------------------------------------------------------------
__global__ __launch_bounds__(256, 2) void attn_kernel(
    const float* __restrict__ x,
    const unsigned short* __restrict__ th,
    const unsigned short* __restrict__ ph,
    const unsigned short* __restrict__ g_t,
    const float* __restrict__ phbar,
    float* __restrict__ out)
{
    __shared__ unsigned short s_ph[2][32*264]; // phi dbuf fp16, padded rows
    __shared__ unsigned short s_p[2][4][16*40];// P dbuf: [buf][wave][16q][32k pad]
    __shared__ float          s_l[64];         // final row sums

    const int tid  = threadIdx.x;
    const int b    = blockIdx.x & 7;           // batch = XCD
    const int q0   = b*NN + (blockIdx.x >> 3)*64;
    const int wv   = tid >> 6;
    const int lane = tid & 63;
    const int quad = lane >> 4;
    const int l15  = lane & 15;

    // staging geometry
    const int sti = tid >> 3;                  // key row 0..31
    const int stc = (tid & 7) * 32;            // 32-channel segment
    const size_t phbase = (size_t)b * MM * CC;
    const unsigned short* stsrc = ph + phbase + (size_t)sti*CC + stc;

    // theta A-frags (fp16) for this wave's 16 rows
    half8 t_hi[8];
    {
        const unsigned short* bh = th + (size_t)(q0 + wv*16 + l15)*CC;
        #pragma unroll
        for (int ks = 0; ks < 8; ++ks)
            t_hi[ks] = *(const half8*)(bh + ks*32 + quad*8);
    }

    // per-row shift = theta . phibar (+128), moved to C-layout rows via shfl
    float sh128[4];
    {
        float sp = 0.f;
        #pragma unroll
        for (int ks = 0; ks < 8; ++ks) {
            const int k0 = ks*32 + quad*8;
            float4v m0 = *(const float4v*)&phbar[b*CC + k0];
            float4v m1 = *(const float4v*)&phbar[b*CC + k0 + 4];
            #pragma unroll
            for (int j = 0; j < 4; ++j) {
                sp += (float)t_hi[ks][j]   * m0[j];
                sp += (float)t_hi[ks][4+j] * m1[j];
            }
        }
        sp += __shfl_xor(sp, 16);
        sp += __shfl_xor(sp, 32);
        #pragma unroll
        for (int r = 0; r < 4; ++r)
            sh128[r] = __shfl(sp, quad*4 + r) + 128.f;
    }

    float4v O[4][4];
    #pragma unroll
    for (int rt = 0; rt < 4; ++rt)
        #pragma unroll
        for (int ct = 0; ct < 4; ++ct) O[rt][ct] = (float4v){0.f,0.f,0.f,0.f};
    float4v accl = (float4v){0.f,0.f,0.f,0.f};

    short8 ones;
    #pragma unroll
    for (int j = 0; j < 8; ++j) ones[j] = (short)0x3F80;   // bf16 1.0

    // this wave's g strip: cols wv*64.., lane row l15, k-offset quad*8
    const unsigned short* gl =
        g_t + ((size_t)b*CC + wv*64 + l15)*MM + quad*8;

    // prologue: stage tile 0 into buf 0
    {
        unsigned short* dh = &s_ph[0][sti*264 + stc];
        #pragma unroll
        for (int u = 0; u < 4; ++u)
            *(uint4*)(dh + u*8) = *(const uint4*)(stsrc + u*8);
    }

    for (int kt = 0; kt < 64; ++kt) {
        const int cur = kt & 1;
        __syncthreads();   // s_ph[cur] staged; s_p[cur^1] complete (kt>0)

        // early global loads: next phi tile + previous tile's g frags
        uint4 stg[4];
        if (kt < 63) {
            const unsigned short* sn = stsrc + (size_t)(kt + 1)*32*CC;
            #pragma unroll
            for (int u = 0; u < 4; ++u) stg[u] = *(const uint4*)(sn + u*8);
        }
        short8 gf[4];
        if (kt > 0) {
            #pragma unroll
            for (int ct = 0; ct < 4; ++ct)
                gf[ct] = *(const short8*)(gl + (size_t)ct*16*MM + (kt-1)*32);
        }

        // S(kt) = theta @ phi^T, 1-pass fp16
        float4v S0 = (float4v){0.f,0.f,0.f,0.f};
        float4v S1 = (float4v){0.f,0.f,0.f,0.f};
        #pragma unroll
        for (int ks = 0; ks < 8; ++ks) {
            half8 b0 = *(const half8*)&s_ph[cur][( 0 + l15)*264 + ks*32 + quad*8];
            half8 b1 = *(const half8*)&s_ph[cur][(16 + l15)*264 + ks*32 + quad*8];
            S0 = __builtin_amdgcn_mfma_f32_16x16x32_f16(t_hi[ks], b0, S0, 0,0,0);
            S1 = __builtin_amdgcn_mfma_f32_16x16x32_f16(t_hi[ks], b1, S1, 0,0,0);
        }

        // PV(kt-1): independent MFMA chain, overlaps S + exp below
        if (kt > 0) {
            #pragma unroll
            for (int rt = 0; rt < 4; ++rt) {
                short8 pA = *(const short8*)&s_p[cur^1][rt][l15*40 + quad*8];
                #pragma unroll
                for (int ct = 0; ct < 4; ++ct)
                    O[rt][ct] = __builtin_amdgcn_mfma_f32_16x16x32_bf16(pA, gf[ct], O[rt][ct], 0,0,0);
            }
        }

        // exp(kt) -> bf16 into s_p[cur][wv]
        unsigned short* pw = &s_p[cur][wv][0];
        #pragma unroll
        for (int r = 0; r < 4; ++r) {
            float a0 = fminf(fmaxf(S0[r] - sh128[r], -85.f), 85.f);
            float a1 = fminf(fmaxf(S1[r] - sh128[r], -85.f), 85.f);
            pw[(quad*4 + r)*40 + l15]      = f2bf(__expf(a0));
            pw[(quad*4 + r)*40 + 16 + l15] = f2bf(__expf(a1));
        }
        asm volatile("s_waitcnt lgkmcnt(0)" ::: "memory");
        short8 pown = *(const short8*)&s_p[cur][wv][l15*40 + quad*8];
        accl = __builtin_amdgcn_mfma_f32_16x16x32_bf16(pown, ones, accl, 0,0,0);

        // stage next phi tile into the other buffer (before next barrier)
        if (kt < 63) {
            unsigned short* dh = &s_ph[cur ^ 1][sti*264 + stc];
            #pragma unroll
            for (int u = 0; u < 4; ++u) *(uint4*)(dh + u*8) = stg[u];
        }
    }

    // drain: PV(63) from s_p[1]
    __syncthreads();
    {
        short8 gf[4];
        #pragma unroll
        for (int ct = 0; ct < 4; ++ct)
            gf[ct] = *(const short8*)(gl + (size_t)ct*16*MM + 63*32);
        #pragma unroll
        for (int rt = 0; rt < 4; ++rt) {
            short8 pA = *(const short8*)&s_p[1][rt][l15*40 + quad*8];
            #pragma unroll
            for (int ct = 0; ct < 4; ++ct)
                O[rt][ct] = __builtin_amdgcn_mfma_f32_16x16x32_bf16(pA, gf[ct], O[rt][ct], 0,0,0);
        }
    }

    // broadcast row sums: wave wv owns l for queries wv*16..wv*16+15
    if (l15 == 0) {
        #pragma unroll
        for (int r = 0; r < 4; ++r) s_l[wv*16 + quad*4 + r] = accl[r];
    }
    __syncthreads();

    // epilogue: y = O/l, out = x + y  (wave wv writes cols wv*64..wv*64+63)
    #pragma unroll
    for (int rt = 0; rt < 4; ++rt) {
        #pragma unroll
        for (int r = 0; r < 4; ++r) {
            const int row = q0 + rt*16 + quad*4 + r;
            const float rl = 1.0f / s_l[rt*16 + quad*4 + r];
            #pragma unroll
            for (int ct = 0; ct < 4; ++ct) {
                const int c = wv*64 + ct*16 + l15;
                const size_t idx = (size_t)row*CC + c;
                out[idx] = x[idx] + O[rt][ct][r] * rl;
            }
        }
    }
}

// ---------------------------------------------------------------------------
extern "C" void kernel_launch(void* const* d_in, const int* in_sizes, int n_in,
                              void* d_out, int out_size, void* d_ws, size_t ws_size,
                              hipStream_t stream) {
    const float* x       = (const float*)d_in[0];
    const float* w_theta = (const float*)d_in[1];
    const float* w_phi   = (const float*)d_in[2];
    const float* w_g     = (const float*)d_in[3];
    float* out = (float*)d_out;

    // workspace (~51.2 MB; verified ws >= 56 MB in round 1)
    unsigned short* th    = (unsigned short*)d_ws;                 // fp16 16.78 MB
    unsigned short* ph    = th    + (size_t)NROWS*CC;              // fp16  8.39 MB
    unsigned short* g_t   = ph    + (size_t)PROWS*CC;              // bf16  8.39 MB
    unsigned short* x_hi  = g_t   + (size_t)PROWS*CC;              // bf16  8.39 MB
    unsigned short* x_lo  = x_hi  + (size_t)NROWS*CC;              // bf16  8.39 MB
    unsigned short* wT_hi = x_lo  + (size_t)NROWS*CC;              // bf16  0.39 MB
    unsigned short* wT_lo = wT_hi + (size_t)3*CC*CC;               // bf16  0.39 MB
    float*          phbar = (float*)(wT_lo + (size_t)3*CC*CC);     // fp32  8 KB

    hipMemsetAsync(phbar, 0, BB*CC*sizeof(float), stream);
    xsplit_kernel<<<NROWS*CC/8/256, 256, 0, stream>>>(x, x_hi, x_lo);
    wsplit_kernel<<<dim3(4,4,3), 256, 0, stream>>>(w_theta, w_phi, w_g, wT_hi, wT_lo);
    proj_kernel<<<1536, 256, 0, stream>>>(x_hi, x_lo, wT_hi, wT_lo, th, ph, g_t);
    phimean_kernel<<<512, 256, 0, stream>>>(ph, phbar);
    attn_kernel<<<NROWS/64, 256, 0, stream>>>(x, th, ph, g_t, phbar, out);
}